// Round 3
// baseline (531.971 us; speedup 1.0000x reference)
//
#include <hip/hip_runtime.h>

#define B   32
#define TK  2048
#define N   1024
#define NF4 256   // N/4
#define NSLICE 32 // t-slices for c_t partials

// out layout (floats): c_t [B*N] at 0, attn_dist [B*TK], coverage_out [B*TK]
#define OUT_CT   0
#define OUT_ATTN (B * N)
#define OUT_COV  (B * N + B * TK)

__device__ __forceinline__ float hw_exp2(float x) {
    return __builtin_amdgcn_exp2f(x);   // v_exp_f32
}

__device__ __forceinline__ float fast_tanh(float x) {
    // tanh(x) = 1 - 2/(exp2(2*log2e*x)+1); stable, saturates to +-1
    float t = hw_exp2(x * 2.8853900817779268f);
    return 1.0f - 2.0f * __builtin_amdgcn_rcpf(t + 1.0f);
}

__device__ __forceinline__ float wave_reduce_sum(float v) {
#pragma unroll
    for (int off = 32; off > 0; off >>= 1) v += __shfl_xor(v, off, 64);
    return v;
}

// Kernel 1: dec_fea[b][n] = sum_k s_t_hat[b][k] * W_dec[n][k] + b_dec[n]
// one wave per (n, group of 4 b). 8192 waves -> 2048 blocks of 256.
__global__ __launch_bounds__(256) void decfea_kernel(
    const float4* __restrict__ S,
    const float4* __restrict__ W,
    const float*  __restrict__ bias,
    float*        __restrict__ dec)
{
    int w    = blockIdx.x * 4 + (threadIdx.x >> 6);
    int lane = threadIdx.x & 63;
    int n    = w >> 3;
    int b0   = (w & 7) * 4;

    float4 wr[4];
#pragma unroll
    for (int j = 0; j < 4; ++j) wr[j] = W[n * NF4 + j * 64 + lane];

#pragma unroll
    for (int i = 0; i < 4; ++i) {
        int b = b0 + i;
        float acc = 0.0f;
#pragma unroll
        for (int j = 0; j < 4; ++j) {
            float4 s4 = S[b * NF4 + j * 64 + lane];
            acc += s4.x * wr[j].x + s4.y * wr[j].y + s4.z * wr[j].z + s4.w * wr[j].w;
        }
        acc = wave_reduce_sum(acc);
        if (lane == 0) dec[b * N + n] = acc + bias[n];
    }
}

// Kernel 2: scores[r] = sum_n tanh(EF[r][n] + dec[b][n] + cov[r]*W_c[n]) * v_w[n]
// 8 rows per wave; wc/vw/dec hoisted to registers (rows of one wave share b).
// 65536 rows / 8 = 8192 waves -> 2048 blocks of 256.
__global__ __launch_bounds__(256) void scores_kernel(
    const float4* __restrict__ EF,
    const float4* __restrict__ DEC,
    const float4* __restrict__ WC,
    const float4* __restrict__ VW,
    const float*  __restrict__ cov,
    float*        __restrict__ scores)
{
    int wave = blockIdx.x * 4 + (threadIdx.x >> 6);  // 0..8191
    int lane = threadIdx.x & 63;
    int r0   = wave * 8;
    int b    = r0 >> 11;  // TK = 2048; all 8 rows share b (aligned)

    float4 wc[4], vw[4], de[4];
#pragma unroll
    for (int j = 0; j < 4; ++j) {
        int f = j * 64 + lane;
        wc[j] = WC[f];
        vw[j] = VW[f];
        de[j] = DEC[b * NF4 + f];
    }

#pragma unroll
    for (int k = 0; k < 8; ++k) {
        int r   = r0 + k;
        float c = cov[r];
        const float4* ef = EF + (size_t)r * NF4;
        float p = 0.0f;
#pragma unroll
        for (int j = 0; j < 4; ++j) {
            float4 e = ef[j * 64 + lane];
            p += fast_tanh(e.x + de[j].x + c * wc[j].x) * vw[j].x;
            p += fast_tanh(e.y + de[j].y + c * wc[j].y) * vw[j].y;
            p += fast_tanh(e.z + de[j].z + c * wc[j].z) * vw[j].z;
            p += fast_tanh(e.w + de[j].w + c * wc[j].w) * vw[j].w;
        }
        p = wave_reduce_sum(p);
        if (lane == 0) scores[r] = p;
    }
}

// Kernel 3: softmax over t per b + mask/renorm/stmt epilogue; writes attn_dist,
// coverage_out into d_out and attn into ws. one block per b.
__global__ __launch_bounds__(256) void softmax_kernel(
    const float* __restrict__ scores,
    const float* __restrict__ mask,
    const float* __restrict__ stmt,
    const float* __restrict__ coverage,
    float*       __restrict__ attn_ws,
    float*       __restrict__ out)
{
    int b = blockIdx.x, tid = threadIdx.x;
    __shared__ float red[256];

    float s[8];
    float m = -1e30f;
#pragma unroll
    for (int k = 0; k < 8; ++k) {
        s[k] = scores[b * TK + k * 256 + tid];
        m = fmaxf(m, s[k]);
    }
    red[tid] = m;
    __syncthreads();
    for (int step = 128; step > 0; step >>= 1) {
        if (tid < step) red[tid] = fmaxf(red[tid], red[tid + step]);
        __syncthreads();
    }
    float M = red[0];
    __syncthreads();

    float e[8];
    float loc = 0.0f;
#pragma unroll
    for (int k = 0; k < 8; ++k) {
        int t = k * 256 + tid;
        e[k] = hw_exp2((s[k] - M) * 1.4426950408889634f) * mask[b * TK + t];
        loc += e[k];
    }
    red[tid] = loc;
    __syncthreads();
    for (int step = 128; step > 0; step >>= 1) {
        if (tid < step) red[tid] += red[tid + step];
        __syncthreads();
    }
    float inv = 1.0f / red[0];

#pragma unroll
    for (int k = 0; k < 8; ++k) {
        int t = k * 256 + tid;
        int r = b * TK + t;
        float a = e[k] * inv + stmt[r] * mask[r];
        attn_ws[r] = a;
        out[OUT_ATTN + r] = a;
        out[OUT_COV + r] = coverage[r] + a;
    }
}

// Kernel 4a: per-slice partials part[s][b][n4] = sum_{t in slice} attn*EO
// grid (NSLICE, B) x 256; 64 t per slice; no atomics.
__global__ __launch_bounds__(256) void ct_part_kernel(
    const float4* __restrict__ EO,
    const float*  __restrict__ attn,
    float4*       __restrict__ part)
{
    int s = blockIdx.x;   // 0..NSLICE-1
    int b = blockIdx.y;   // 0..B-1
    int tid = threadIdx.x;

    __shared__ float wbuf[TK / NSLICE];   // 64
    if (tid < TK / NSLICE) wbuf[tid] = attn[b * TK + s * (TK / NSLICE) + tid];
    __syncthreads();

    float4 acc = {0.0f, 0.0f, 0.0f, 0.0f};
    const float4* eo = EO + ((size_t)b * TK + s * (TK / NSLICE)) * NF4 + tid;
#pragma unroll 8
    for (int t = 0; t < TK / NSLICE; ++t) {
        float w  = wbuf[t];
        float4 v = eo[(size_t)t * NF4];
        acc.x += w * v.x;
        acc.y += w * v.y;
        acc.z += w * v.z;
        acc.w += w * v.w;
    }
    part[((size_t)s * B + b) * NF4 + tid] = acc;
}

// Kernel 4b: c_t = sum over slices. 8192 float4 outputs; 32 blocks x 256.
__global__ __launch_bounds__(256) void ct_reduce_kernel(
    const float4* __restrict__ part,
    float4*       __restrict__ ct)
{
    int idx = blockIdx.x * 256 + threadIdx.x;   // 0..8191
    float4 a = {0.0f, 0.0f, 0.0f, 0.0f};
#pragma unroll
    for (int s = 0; s < NSLICE; ++s) {
        float4 v = part[(size_t)s * (B * NF4) + idx];
        a.x += v.x; a.y += v.y; a.z += v.z; a.w += v.w;
    }
    ct[idx] = a;
}

extern "C" void kernel_launch(void* const* d_in, const int* in_sizes, int n_in,
                              void* d_out, int out_size, void* d_ws, size_t ws_size,
                              hipStream_t stream) {
    const float* s_t_hat = (const float*)d_in[0];
    const float* EO      = (const float*)d_in[1];
    const float* EF      = (const float*)d_in[2];
    const float* stmt    = (const float*)d_in[3];
    const float* mask    = (const float*)d_in[4];
    const float* cov     = (const float*)d_in[5];
    const float* Wdec    = (const float*)d_in[6];
    const float* bdec    = (const float*)d_in[7];
    const float* vw      = (const float*)d_in[8];
    const float* wc      = (const float*)d_in[9];

    float* out = (float*)d_out;
    float* ws  = (float*)d_ws;
    float* dec    = ws;                          // 32768 floats
    float* scores = ws + B * N;                  // 65536 floats
    float* attn   = ws + B * N + B * TK;         // 65536 floats
    float* part   = ws + B * N + 2 * B * TK;     // NSLICE*B*N = 1M floats (4 MB)

    decfea_kernel<<<2048, 256, 0, stream>>>(
        (const float4*)s_t_hat, (const float4*)Wdec, bdec, dec);

    scores_kernel<<<2048, 256, 0, stream>>>(
        (const float4*)EF, (const float4*)dec, (const float4*)wc,
        (const float4*)vw, cov, scores);

    softmax_kernel<<<B, 256, 0, stream>>>(scores, mask, stmt, cov, attn, out);

    ct_part_kernel<<<dim3(NSLICE, B), 256, 0, stream>>>(
        (const float4*)EO, attn, (float4*)part);

    ct_reduce_kernel<<<B, 256, 0, stream>>>(
        (const float4*)part, (float4*)(out + OUT_CT));
}